// Round 5
// baseline (482.696 us; speedup 1.0000x reference)
//
#include <hip/hip_runtime.h>
#include <hip/hip_cooperative_groups.h>

namespace cg = cooperative_groups;

// Problem constants (from reference setup_inputs)
#define N_PRE_C   50000
#define N_TYPES_C 20
#define N_BASIS_C 5
#define NB        2                    // batches
#define WORDS32   1568                 // ceil(50000/32)=1563, padded to 1568 (wave-aligned)
#define PACK_LANES (NB * WORDS32 * 32) // 100352 ballot lanes (wave-aligned per batch)

typedef unsigned long long ull;
typedef unsigned int uint_t;

// ---------------------------------------------------------------------------
// FUSED cooperative kernel: pack + zero | grid.sync | scatter | grid.sync |
// combine. One dispatch instead of four: R0-R4 accounting shows ~130us of the
// ~196us total is inter-dispatch overhead (GPU work outside scatter is ~6us).
// Scatter body is IDENTICAL to R4's best (8B mask lookups, predicated w/sid,
// fire-and-forget atomics) - this round varies only the dispatch structure.
// __threadfence() around grid.sync(): belt-and-suspenders L2 wb/inv so
// phase-2 plain loads can't hit stale zeroed lines in a non-coherent XCD L2.
// ---------------------------------------------------------------------------
__global__ __launch_bounds__(256) void fused_all(
    const float* __restrict__ rec_z,
    const float4* __restrict__ w4,
    const float* __restrict__ basis,
    const int4*  __restrict__ idx2,    // 2 synapses per int4 (post,pre,post,pre)
    const int4*  __restrict__ sid4,
    uint_t* __restrict__ mask32,       // [WORDS32][NB] in ws
    float*  __restrict__ out_t,        // [NB*n_post][N_TYPES] accumulator in ws
    float*  __restrict__ out,          // [rows][N_BASIS] final
    int n_post, int n_syn, int rows) {
    __shared__ __align__(16) uint2 sm[WORDS32];
    __shared__ float sb[N_TYPES_C * N_BASIS_C];

    const int tid = threadIdx.x;
    const int gid = blockIdx.x * 256 + tid;
    const int nthreads = gridDim.x * 256;

    // ---- phase 0: stage basis (LDS persists), pack mask, zero out_t ----
    if (tid < N_TYPES_C * N_BASIS_C) sb[tid] = basis[tid];

    if (gid < PACK_LANES) {
        const int b = gid / (WORDS32 * 32);
        const int i = gid % (WORDS32 * 32);      // wave-aligned: 50176 % 64 == 0
        float v = 0.f;
        if (i < N_PRE_C) v = rec_z[b * N_PRE_C + i];
        const ull m = __ballot(v > 0.f);
        if ((tid & 63) == 0) {                   // i is a multiple of 64 here
            const int w32 = i >> 5;              // even
            mask32[(w32 + 0) * NB + b] = (uint_t)(m & 0xffffffffull);
            mask32[(w32 + 1) * NB + b] = (uint_t)(m >> 32);
        }
    }
    {
        const int zq = rows * N_TYPES_C / 4;     // 80B/row -> multiple of 16B
        float4* zp = (float4*)out_t;
        const float4 z = make_float4(0.f, 0.f, 0.f, 0.f);
        for (int q = gid; q < zq; q += nthreads) zp[q] = z;
    }

    __threadfence();                 // release zero-stores + mask to device scope
    cg::this_grid().sync();
    __threadfence();                 // acquire (L2 inv) before reading mask

    // ---- phase 1: stage mask to LDS, grid-stride scatter (R4 body) ----
    {
        const uint4* msrc = (const uint4*)mask32;
        uint4* mdst = (uint4*)sm;
        for (int t = tid; t < WORDS32 / 2; t += 256) mdst[t] = msrc[t];
    }
    __syncthreads();

    const int np20 = n_post * N_TYPES_C;
    const int nq = n_syn >> 2;                   // whole quads
    for (int t = gid; t < nq; t += nthreads) {
        const int4 p01 = idx2[(long)t * 2];
        const int4 p23 = idx2[(long)t * 2 + 1];
        const uint2 m0 = sm[p01.y >> 5];
        const uint2 m1 = sm[p01.w >> 5];
        const uint2 m2 = sm[p23.y >> 5];
        const uint2 m3 = sm[p23.w >> 5];
        const uint_t b0 = 1u << (p01.y & 31);
        const uint_t b1 = 1u << (p01.w & 31);
        const uint_t b2 = 1u << (p23.y & 31);
        const uint_t b3 = 1u << (p23.w & 31);
        const uint_t f0 = (m0.x | m0.y) & b0;
        const uint_t f1 = (m1.x | m1.y) & b1;
        const uint_t f2 = (m2.x | m2.y) & b2;
        const uint_t f3 = (m3.x | m3.y) & b3;
        if (f0 | f1 | f2 | f3) {                 // ~15% of threads
            const float4 wv = w4[t];             // predicated 16B loads
            const int4   sv = sid4[t];
            if (f0) {
                const int o = p01.x * N_TYPES_C + sv.x;
                if (m0.x & b0) unsafeAtomicAdd(out_t + o, wv.x);
                if (m0.y & b0) unsafeAtomicAdd(out_t + o + np20, wv.x);
            }
            if (f1) {
                const int o = p01.z * N_TYPES_C + sv.y;
                if (m1.x & b1) unsafeAtomicAdd(out_t + o, wv.y);
                if (m1.y & b1) unsafeAtomicAdd(out_t + o + np20, wv.y);
            }
            if (f2) {
                const int o = p23.x * N_TYPES_C + sv.z;
                if (m2.x & b2) unsafeAtomicAdd(out_t + o, wv.z);
                if (m2.y & b2) unsafeAtomicAdd(out_t + o + np20, wv.z);
            }
            if (f3) {
                const int o = p23.z * N_TYPES_C + sv.w;
                if (m3.x & b3) unsafeAtomicAdd(out_t + o, wv.w);
                if (m3.y & b3) unsafeAtomicAdd(out_t + o + np20, wv.w);
            }
        }
    }
    // scalar tail (n_syn % 4), handled by block 0
    const int rem = n_syn & 3;
    if (blockIdx.x == 0 && tid < rem) {
        const long s = (long)(n_syn & ~3) + tid;
        const int*   idx = (const int*)idx2;
        const float* w   = (const float*)w4;
        const int*   sid = (const int*)sid4;
        const int post = idx[2 * s], pre = idx[2 * s + 1];
        const uint2 mw = sm[pre >> 5];
        const uint_t bit = 1u << (pre & 31);
        if ((mw.x | mw.y) & bit) {
            const int o = post * N_TYPES_C + sid[s];
            if (mw.x & bit) unsafeAtomicAdd(out_t + o, w[s]);
            if (mw.y & bit) unsafeAtomicAdd(out_t + o + np20, w[s]);
        }
    }

    __threadfence();                 // release atomics
    cg::this_grid().sync();
    __threadfence();                 // acquire: invalidate stale out_t lines

    // ---- phase 2: combine out_t [rows][20] x basis [20][5] -> out ----
    for (int r = gid; r < rows; r += nthreads) {
        const float4* p = (const float4*)(out_t + (long)r * N_TYPES_C);
        float4 v0 = p[0], v1 = p[1], v2 = p[2], v3 = p[3], v4 = p[4];
        float vt[N_TYPES_C] = {v0.x, v0.y, v0.z, v0.w, v1.x, v1.y, v1.z, v1.w,
                               v2.x, v2.y, v2.z, v2.w, v3.x, v3.y, v3.z, v3.w,
                               v4.x, v4.y, v4.z, v4.w};
        float acc[N_BASIS_C] = {0.f, 0.f, 0.f, 0.f, 0.f};
        #pragma unroll
        for (int t = 0; t < N_TYPES_C; ++t) {
            #pragma unroll
            for (int k = 0; k < N_BASIS_C; ++k)
                acc[k] += vt[t] * sb[t * N_BASIS_C + k];
        }
        float* o = out + (long)r * N_BASIS_C;
        #pragma unroll
        for (int k = 0; k < N_BASIS_C; ++k) o[k] = acc[k];
    }
}

// ===========================================================================
// Fallback multi-kernel path (used if cooperative launch unavailable or ws
// too small) - R4 kernels, proven correct.
// ===========================================================================
__global__ __launch_bounds__(256) void pack_spikes(const float* __restrict__ rec_z,
                                                   uint_t* __restrict__ mask32,
                                                   float4* __restrict__ zbuf,
                                                   int zquads) {
    const int b = blockIdx.y;
    const int i = blockIdx.x * 256 + threadIdx.x;
    float v = 0.f;
    if (i < N_PRE_C) v = rec_z[b * N_PRE_C + i];
    const ull m = __ballot(v > 0.f);
    if ((threadIdx.x & 63) == 0) {
        const int w32 = i >> 5;
        mask32[(w32 + 0) * NB + b] = (uint_t)(m & 0xffffffffull);
        mask32[(w32 + 1) * NB + b] = (uint_t)(m >> 32);
    }
    if (zbuf != nullptr) {
        const int nt = gridDim.x * gridDim.y * 256;
        int q = (blockIdx.y * gridDim.x + blockIdx.x) * 256 + threadIdx.x;
        const float4 z = make_float4(0.f, 0.f, 0.f, 0.f);
        for (; q < zquads; q += nt) zbuf[q] = z;
    }
}

__global__ __launch_bounds__(256) void syn_scatter_t(
    const int4*  __restrict__ idx2,
    const float4* __restrict__ w4,
    const int4*  __restrict__ sid4,
    const uint2* __restrict__ mask2,
    float* __restrict__ out_t,
    int n_post, int n_syn) {
    __shared__ __align__(16) uint2 sm[WORDS32];
    {
        const uint4* msrc = (const uint4*)mask2;
        uint4* mdst = (uint4*)sm;
        for (int t = threadIdx.x; t < WORDS32 / 2; t += 256) mdst[t] = msrc[t];
    }
    __syncthreads();
    const int t = blockIdx.x * 256 + threadIdx.x;
    const long base = (long)t * 4;
    if (base >= n_syn) return;
    const int np20 = n_post * N_TYPES_C;
    if (base + 4 <= n_syn) {
        const int4 p01 = idx2[t * 2];
        const int4 p23 = idx2[t * 2 + 1];
        const uint2 m0 = sm[p01.y >> 5];
        const uint2 m1 = sm[p01.w >> 5];
        const uint2 m2 = sm[p23.y >> 5];
        const uint2 m3 = sm[p23.w >> 5];
        const uint_t b0 = 1u << (p01.y & 31);
        const uint_t b1 = 1u << (p01.w & 31);
        const uint_t b2 = 1u << (p23.y & 31);
        const uint_t b3 = 1u << (p23.w & 31);
        const uint_t f0 = (m0.x | m0.y) & b0;
        const uint_t f1 = (m1.x | m1.y) & b1;
        const uint_t f2 = (m2.x | m2.y) & b2;
        const uint_t f3 = (m3.x | m3.y) & b3;
        if (f0 | f1 | f2 | f3) {
            const float4 wv = w4[t];
            const int4   sv = sid4[t];
            if (f0) {
                const int o = p01.x * N_TYPES_C + sv.x;
                if (m0.x & b0) unsafeAtomicAdd(out_t + o, wv.x);
                if (m0.y & b0) unsafeAtomicAdd(out_t + o + np20, wv.x);
            }
            if (f1) {
                const int o = p01.z * N_TYPES_C + sv.y;
                if (m1.x & b1) unsafeAtomicAdd(out_t + o, wv.y);
                if (m1.y & b1) unsafeAtomicAdd(out_t + o + np20, wv.y);
            }
            if (f2) {
                const int o = p23.x * N_TYPES_C + sv.z;
                if (m2.x & b2) unsafeAtomicAdd(out_t + o, wv.z);
                if (m2.y & b2) unsafeAtomicAdd(out_t + o + np20, wv.z);
            }
            if (f3) {
                const int o = p23.z * N_TYPES_C + sv.w;
                if (m3.x & b3) unsafeAtomicAdd(out_t + o, wv.w);
                if (m3.y & b3) unsafeAtomicAdd(out_t + o + np20, wv.w);
            }
        }
    } else {
        const int*   idx = (const int*)idx2;
        const float* w   = (const float*)w4;
        const int*   sid = (const int*)sid4;
        for (long s = base; s < n_syn; ++s) {
            const int post = idx[2 * s], pre = idx[2 * s + 1];
            const uint2 mw = sm[pre >> 5];
            const uint_t bit = 1u << (pre & 31);
            if (((mw.x | mw.y) & bit) == 0u) continue;
            const int o = post * N_TYPES_C + sid[s];
            if (mw.x & bit) unsafeAtomicAdd(out_t + o, w[s]);
            if (mw.y & bit) unsafeAtomicAdd(out_t + o + np20, w[s]);
        }
    }
}

__global__ __launch_bounds__(256) void combine_basis(
    const float* __restrict__ out_t,
    const float* __restrict__ basis,
    float* __restrict__ out, int rows) {
    __shared__ float sb[N_TYPES_C * N_BASIS_C];
    if (threadIdx.x < N_TYPES_C * N_BASIS_C) sb[threadIdx.x] = basis[threadIdx.x];
    __syncthreads();
    const int r = blockIdx.x * 256 + threadIdx.x;
    if (r >= rows) return;
    const float4* p = (const float4*)(out_t + (long)r * N_TYPES_C);
    float4 v0 = p[0], v1 = p[1], v2 = p[2], v3 = p[3], v4 = p[4];
    float vt[N_TYPES_C] = {v0.x, v0.y, v0.z, v0.w, v1.x, v1.y, v1.z, v1.w,
                           v2.x, v2.y, v2.z, v2.w, v3.x, v3.y, v3.z, v3.w,
                           v4.x, v4.y, v4.z, v4.w};
    float acc[N_BASIS_C] = {0.f, 0.f, 0.f, 0.f, 0.f};
    #pragma unroll
    for (int t = 0; t < N_TYPES_C; ++t) {
        #pragma unroll
        for (int k = 0; k < N_BASIS_C; ++k)
            acc[k] += vt[t] * sb[t * N_BASIS_C + k];
    }
    float* o = out + (long)r * N_BASIS_C;
    #pragma unroll
    for (int k = 0; k < N_BASIS_C; ++k) o[k] = acc[k];
}

__global__ __launch_bounds__(256) void syn_scatter_direct(
    const int4* __restrict__ idx2, const float4* __restrict__ w4,
    const int4* __restrict__ sid4, const float* __restrict__ basis,
    const uint2* __restrict__ mask2, float* __restrict__ out,
    int n_post, int n_syn) {
    __shared__ __align__(16) uint2 sm[WORDS32];
    __shared__ float sb[N_TYPES_C][N_BASIS_C];
    for (int t = threadIdx.x; t < WORDS32; t += 256) sm[t] = mask2[t];
    for (int t = threadIdx.x; t < N_TYPES_C * N_BASIS_C; t += 256)
        ((float*)sb)[t] = basis[t];
    __syncthreads();
    const int t = blockIdx.x * 256 + threadIdx.x;
    const long base = (long)t * 4;
    if (base >= n_syn) return;
    auto apply = [&](int post, int pre, float wv, int tt) {
        const uint2 mw = sm[pre >> 5];
        const uint_t bit = 1u << (pre & 31);
        if (((mw.x | mw.y) & bit) == 0u) return;
        const float* bs = sb[tt];
        float c[N_BASIS_C];
        #pragma unroll
        for (int k = 0; k < N_BASIS_C; ++k) c[k] = wv * bs[k];
        if (mw.x & bit) {
            float* o = out + (long)post * N_BASIS_C;
            #pragma unroll
            for (int k = 0; k < N_BASIS_C; ++k) unsafeAtomicAdd(o + k, c[k]);
        }
        if (mw.y & bit) {
            float* o = out + (long)(n_post + post) * N_BASIS_C;
            #pragma unroll
            for (int k = 0; k < N_BASIS_C; ++k) unsafeAtomicAdd(o + k, c[k]);
        }
    };
    if (base + 4 <= n_syn) {
        const int4   p01 = idx2[t * 2];
        const int4   p23 = idx2[t * 2 + 1];
        const float4 wv  = w4[t];
        const int4   sv  = sid4[t];
        apply(p01.x, p01.y, wv.x, sv.x);
        apply(p01.z, p01.w, wv.y, sv.y);
        apply(p23.x, p23.y, wv.z, sv.z);
        apply(p23.z, p23.w, wv.w, sv.w);
    } else {
        const int*   idx = (const int*)idx2;
        const float* w   = (const float*)w4;
        const int*   sid = (const int*)sid4;
        for (long s = base; s < n_syn; ++s)
            apply(idx[2 * s], idx[2 * s + 1], w[s], sid[s]);
    }
}

extern "C" void kernel_launch(void* const* d_in, const int* in_sizes, int n_in,
                              void* d_out, int out_size, void* d_ws, size_t ws_size,
                              hipStream_t stream) {
    const float* rec_z   = (const float*)d_in[0];
    const float* weights = (const float*)d_in[1];
    const float* basis   = (const float*)d_in[2];
    const int*   synidx  = (const int*)d_in[3];
    const int*   synids  = (const int*)d_in[4];
    float*       out     = (float*)d_out;

    const int n_syn  = in_sizes[4];
    const int rows   = out_size / N_BASIS_C;       // NB * n_post
    const int n_post = rows / NB;

    // Workspace layout: out_t [rows][N_TYPES] floats, then mask32.
    const size_t out_t_bytes = (size_t)rows * N_TYPES_C * sizeof(float);  // mult of 16
    const size_t mask_bytes  = (size_t)WORDS32 * NB * sizeof(uint_t);

    // One-time: max co-resident blocks for the fused cooperative kernel.
    static int coop_blocks = -2;
    if (coop_blocks == -2) {
        int dev = 0, maxb = 0, ncu = 0;
        if (hipGetDevice(&dev) == hipSuccess) {
            hipDeviceProp_t prop;
            if (hipGetDeviceProperties(&prop, dev) == hipSuccess)
                ncu = prop.multiProcessorCount;
            if (hipOccupancyMaxActiveBlocksPerMultiprocessor(
                    &maxb, (const void*)fused_all, 256, 0) != hipSuccess)
                maxb = 0;
        }
        long g = (long)maxb * ncu;
        if (g > 2048) g = 2048;                    // 8/CU is plenty of TLP
        coop_blocks = (g >= 256) ? (int)g : -1;    // -1 = coop unusable
    }

    if (ws_size >= out_t_bytes + mask_bytes && coop_blocks > 0) {
        float*  out_t  = (float*)d_ws;
        uint_t* mask32 = (uint_t*)((char*)d_ws + out_t_bytes);

        void* args[] = {(void*)&rec_z, (void*)&weights, (void*)&basis,
                        (void*)&synidx, (void*)&synids, (void*)&mask32,
                        (void*)&out_t, (void*)&out,
                        (void*)&n_post, (void*)&n_syn, (void*)&rows};
        const hipError_t e = hipLaunchCooperativeKernel(
            (const void*)fused_all, dim3(coop_blocks), dim3(256),
            args, 0, stream);
        if (e == hipSuccess) return;
        coop_blocks = -1;                          // don't retry; fall through
    }

    if (ws_size >= out_t_bytes + mask_bytes) {
        // Fallback A: proven R4 three-kernel path.
        float*  out_t  = (float*)d_ws;
        uint_t* mask32 = (uint_t*)((char*)d_ws + out_t_bytes);
        const int zquads = (int)(out_t_bytes / sizeof(float4));
        pack_spikes<<<dim3(WORDS32 * 32 / 256, NB), 256, 0, stream>>>(
            rec_z, mask32, (float4*)out_t, zquads);
        const int blocks = ((n_syn + 3) / 4 + 255) / 256;
        syn_scatter_t<<<blocks, 256, 0, stream>>>(
            (const int4*)synidx, (const float4*)weights, (const int4*)synids,
            (const uint2*)mask32, out_t, n_post, n_syn);
        combine_basis<<<(rows + 255) / 256, 256, 0, stream>>>(out_t, basis, out, rows);
    } else {
        // Fallback B: direct 5-atomic scatter (tiny ws).
        uint_t* mask32 = (uint_t*)d_ws;
        hipMemsetAsync(d_out, 0, (size_t)out_size * sizeof(float), stream);
        pack_spikes<<<dim3(WORDS32 * 32 / 256, NB), 256, 0, stream>>>(
            rec_z, mask32, nullptr, 0);
        const int blocks = ((n_syn + 3) / 4 + 255) / 256;
        syn_scatter_direct<<<blocks, 256, 0, stream>>>(
            (const int4*)synidx, (const float4*)weights, (const int4*)synids,
            basis, (const uint2*)mask32, out, n_post, n_syn);
    }
}

// Round 6
// 195.667 us; speedup vs baseline: 2.4669x; 2.4669x over previous
//
#include <hip/hip_runtime.h>

// Problem constants (from reference setup_inputs)
#define N_PRE_C   50000
#define N_TYPES_C 20
#define N_BASIS_C 5
#define NB        2                    // batches
#define WORDS32   1568                 // ceil(50000/32)=1563, padded to 1568 (wave-aligned)

typedef unsigned long long ull;
typedef unsigned int uint_t;

// ---------------------------------------------------------------------------
// Kernel 1: pack rec_z_buf (B x N_PRE floats, binary) into a 32-bit bitmask.
// Layout: mask32[word32][b] so one 8B uint2 read covers both batches.
// Also zeroes out_t (grid-stride float4): no separate memset dispatch.
// ---------------------------------------------------------------------------
__global__ __launch_bounds__(256) void pack_spikes(const float* __restrict__ rec_z,
                                                   uint_t* __restrict__ mask32,
                                                   float4* __restrict__ zbuf,
                                                   int zquads) {
    const int b = blockIdx.y;
    const int i = blockIdx.x * 256 + threadIdx.x;   // [0, WORDS32*32)
    float v = 0.f;
    if (i < N_PRE_C) v = rec_z[b * N_PRE_C + i];
    const ull m = __ballot(v > 0.f);
    if ((threadIdx.x & 63) == 0) {                  // i is a multiple of 64
        const int w32 = i >> 5;                     // even
        mask32[(w32 + 0) * NB + b] = (uint_t)(m & 0xffffffffull);
        mask32[(w32 + 1) * NB + b] = (uint_t)(m >> 32);
    }
    if (zbuf != nullptr) {
        const int nt = gridDim.x * gridDim.y * 256;
        int q = (blockIdx.y * gridDim.x + blockIdx.x) * 256 + threadIdx.x;
        const float4 z = make_float4(0.f, 0.f, 0.f, 0.f);
        for (; q < zquads; q += nt) zbuf[q] = z;
    }
}

// ---------------------------------------------------------------------------
// Kernel 2: one-shot scatter, NO LDS, NO barrier, minimum dependency depth.
//  - 8 synapses/thread; 8 independent 16B loads (idx/w/sid) issued up front
//    (R0-style unconditional: proven fastest per byte; no dependent 2nd HBM
//    stage like R4's predicated loads).
//  - mask lookups are plain global 8B loads: the 12.5KB mask is L1-resident
//    per CU (32KB L1). No staging loop, no __syncthreads, no block prologue.
//  - Per-thread graph: {8 streaming loads} -> {8 indep gathers} -> atomics.
// unsafeAtomicAdd = HW global_atomic_add_f32, no return (fire-and-forget).
// ---------------------------------------------------------------------------
__global__ __launch_bounds__(256) void syn_scatter_t(
    const int4*  __restrict__ idx2,    // 2 synapses per int4 (post,pre,post,pre)
    const float4* __restrict__ w4,
    const int4*  __restrict__ sid4,
    const uint2* __restrict__ mask2,   // [WORDS32] {b0,b1}, read via L1
    float* __restrict__ out_t,         // [NB*n_post][N_TYPES] accumulator (zeroed)
    int n_post, int n_syn) {
    const int t = blockIdx.x * 256 + threadIdx.x;
    const long base = (long)t * 8;
    if (base >= n_syn) return;
    const int np20 = n_post * N_TYPES_C;

    auto one = [&](int post, int pre_bit_fire_x, int pre_bit_fire_y,
                   float wv, int tt) {
        // (resolved by caller; kept for clarity)
    };
    (void)one;

    if (base + 8 <= n_syn) {
        // ---- stage 1: 8 independent coalesced 16B loads (128B/thread) ----
        const int4   pA = idx2[(long)t * 4 + 0];
        const int4   pB = idx2[(long)t * 4 + 1];
        const int4   pC = idx2[(long)t * 4 + 2];
        const int4   pD = idx2[(long)t * 4 + 3];
        const float4 wA = w4[(long)t * 2 + 0];
        const float4 wB = w4[(long)t * 2 + 1];
        const int4   sA = sid4[(long)t * 2 + 0];
        const int4   sB = sid4[(long)t * 2 + 1];
        // ---- stage 2: 8 independent 8B gathers from L1-resident mask ----
        const uint2 m0 = mask2[pA.y >> 5];
        const uint2 m1 = mask2[pA.w >> 5];
        const uint2 m2 = mask2[pB.y >> 5];
        const uint2 m3 = mask2[pB.w >> 5];
        const uint2 m4 = mask2[pC.y >> 5];
        const uint2 m5 = mask2[pC.w >> 5];
        const uint2 m6 = mask2[pD.y >> 5];
        const uint2 m7 = mask2[pD.w >> 5];
        // ---- stage 3: bit tests + fire-and-forget atomics ----
        #define ONE(POST, PRE, MW, WV, TT)                                    \
            {                                                                 \
                const uint_t bit = 1u << ((PRE) & 31);                        \
                if ((((MW).x | (MW).y) & bit) != 0u) {                        \
                    const int o = (POST) * N_TYPES_C + (TT);                  \
                    if ((MW).x & bit) unsafeAtomicAdd(out_t + o, (WV));       \
                    if ((MW).y & bit) unsafeAtomicAdd(out_t + o + np20, (WV));\
                }                                                             \
            }
        ONE(pA.x, pA.y, m0, wA.x, sA.x)
        ONE(pA.z, pA.w, m1, wA.y, sA.y)
        ONE(pB.x, pB.y, m2, wA.z, sA.z)
        ONE(pB.z, pB.w, m3, wA.w, sA.w)
        ONE(pC.x, pC.y, m4, wB.x, sB.x)
        ONE(pC.z, pC.w, m5, wB.y, sB.y)
        ONE(pD.x, pD.y, m6, wB.z, sB.z)
        ONE(pD.z, pD.w, m7, wB.w, sB.w)
        #undef ONE
    } else {
        const int*   idx = (const int*)idx2;
        const float* w   = (const float*)w4;
        const int*   sid = (const int*)sid4;
        for (long s = base; s < n_syn; ++s) {
            const int post = idx[2 * s], pre = idx[2 * s + 1];
            const uint2 mw = mask2[pre >> 5];
            const uint_t bit = 1u << (pre & 31);
            if (((mw.x | mw.y) & bit) == 0u) continue;
            const int o = post * N_TYPES_C + sid[s];
            if (mw.x & bit) unsafeAtomicAdd(out_t + o, w[s]);
            if (mw.y & bit) unsafeAtomicAdd(out_t + o + np20, w[s]);
        }
    }
}

// ---------------------------------------------------------------------------
// Kernel 3: combine out_t [rows][20] x basis [20][5] -> out [rows][5].
// ---------------------------------------------------------------------------
__global__ __launch_bounds__(256) void combine_basis(
    const float* __restrict__ out_t,
    const float* __restrict__ basis,   // [N_TYPES][N_BASIS]
    float* __restrict__ out, int rows) {
    __shared__ float sb[N_TYPES_C * N_BASIS_C];
    if (threadIdx.x < N_TYPES_C * N_BASIS_C) sb[threadIdx.x] = basis[threadIdx.x];
    __syncthreads();

    const int r = blockIdx.x * 256 + threadIdx.x;
    if (r >= rows) return;
    const float4* p = (const float4*)(out_t + (long)r * N_TYPES_C);
    float4 v0 = p[0], v1 = p[1], v2 = p[2], v3 = p[3], v4 = p[4];
    float vt[N_TYPES_C] = {v0.x, v0.y, v0.z, v0.w, v1.x, v1.y, v1.z, v1.w,
                           v2.x, v2.y, v2.z, v2.w, v3.x, v3.y, v3.z, v3.w,
                           v4.x, v4.y, v4.z, v4.w};
    float acc[N_BASIS_C] = {0.f, 0.f, 0.f, 0.f, 0.f};
    #pragma unroll
    for (int t = 0; t < N_TYPES_C; ++t) {
        #pragma unroll
        for (int k = 0; k < N_BASIS_C; ++k)
            acc[k] += vt[t] * sb[t * N_BASIS_C + k];   // sb read is a broadcast
    }
    float* o = out + (long)r * N_BASIS_C;
    #pragma unroll
    for (int k = 0; k < N_BASIS_C; ++k) o[k] = acc[k];
}

// ---------------------------------------------------------------------------
// Fallback (only if ws too small): direct 5-atomic scatter into out.
// ---------------------------------------------------------------------------
__global__ __launch_bounds__(256) void syn_scatter_direct(
    const int4* __restrict__ idx2, const float4* __restrict__ w4,
    const int4* __restrict__ sid4, const float* __restrict__ basis,
    const uint2* __restrict__ mask2, float* __restrict__ out,
    int n_post, int n_syn) {
    __shared__ float sb[N_TYPES_C][N_BASIS_C];
    for (int t = threadIdx.x; t < N_TYPES_C * N_BASIS_C; t += 256)
        ((float*)sb)[t] = basis[t];
    __syncthreads();
    const int t = blockIdx.x * 256 + threadIdx.x;
    const long base = (long)t * 4;
    if (base >= n_syn) return;

    auto apply = [&](int post, int pre, float wv, int tt) {
        const uint2 mw = mask2[pre >> 5];
        const uint_t bit = 1u << (pre & 31);
        if (((mw.x | mw.y) & bit) == 0u) return;
        const float* bs = sb[tt];
        float c[N_BASIS_C];
        #pragma unroll
        for (int k = 0; k < N_BASIS_C; ++k) c[k] = wv * bs[k];
        if (mw.x & bit) {
            float* o = out + (long)post * N_BASIS_C;
            #pragma unroll
            for (int k = 0; k < N_BASIS_C; ++k) unsafeAtomicAdd(o + k, c[k]);
        }
        if (mw.y & bit) {
            float* o = out + (long)(n_post + post) * N_BASIS_C;
            #pragma unroll
            for (int k = 0; k < N_BASIS_C; ++k) unsafeAtomicAdd(o + k, c[k]);
        }
    };

    if (base + 4 <= n_syn) {
        const int4   p01 = idx2[t * 2];
        const int4   p23 = idx2[t * 2 + 1];
        const float4 wv  = w4[t];
        const int4   sv  = sid4[t];
        apply(p01.x, p01.y, wv.x, sv.x);
        apply(p01.z, p01.w, wv.y, sv.y);
        apply(p23.x, p23.y, wv.z, sv.z);
        apply(p23.z, p23.w, wv.w, sv.w);
    } else {
        const int*   idx = (const int*)idx2;
        const float* w   = (const float*)w4;
        const int*   sid = (const int*)sid4;
        for (long s = base; s < n_syn; ++s)
            apply(idx[2 * s], idx[2 * s + 1], w[s], sid[s]);
    }
}

extern "C" void kernel_launch(void* const* d_in, const int* in_sizes, int n_in,
                              void* d_out, int out_size, void* d_ws, size_t ws_size,
                              hipStream_t stream) {
    const float* rec_z   = (const float*)d_in[0];
    const float* weights = (const float*)d_in[1];
    const float* basis   = (const float*)d_in[2];
    const int*   synidx  = (const int*)d_in[3];
    const int*   synids  = (const int*)d_in[4];
    float*       out     = (float*)d_out;

    const int n_syn  = in_sizes[4];
    const int rows   = out_size / N_BASIS_C;       // NB * n_post
    const int n_post = rows / NB;

    // Workspace layout: out_t [rows][N_TYPES] floats, then mask32.
    const size_t out_t_bytes = (size_t)rows * N_TYPES_C * sizeof(float);  // mult of 16
    const size_t mask_bytes  = (size_t)WORDS32 * NB * sizeof(uint_t);

    if (ws_size >= out_t_bytes + mask_bytes) {
        float*  out_t  = (float*)d_ws;
        uint_t* mask32 = (uint_t*)((char*)d_ws + out_t_bytes);

        const int zquads = (int)(out_t_bytes / sizeof(float4));
        pack_spikes<<<dim3(WORDS32 * 32 / 256, NB), 256, 0, stream>>>(
            rec_z, mask32, (float4*)out_t, zquads);

        const int n_thr  = (n_syn + 7) / 8;        // 8 synapses per thread
        const int blocks = (n_thr + 255) / 256;
        syn_scatter_t<<<blocks, 256, 0, stream>>>(
            (const int4*)synidx, (const float4*)weights, (const int4*)synids,
            (const uint2*)mask32, out_t, n_post, n_syn);

        combine_basis<<<(rows + 255) / 256, 256, 0, stream>>>(out_t, basis, out, rows);
    } else {
        // Fallback: direct 5-atomic scatter (tiny ws).
        uint_t* mask32 = (uint_t*)d_ws;
        hipMemsetAsync(d_out, 0, (size_t)out_size * sizeof(float), stream);
        pack_spikes<<<dim3(WORDS32 * 32 / 256, NB), 256, 0, stream>>>(
            rec_z, mask32, nullptr, 0);
        const int blocks = ((n_syn + 3) / 4 + 255) / 256;
        syn_scatter_direct<<<blocks, 256, 0, stream>>>(
            (const int4*)synidx, (const float4*)weights, (const int4*)synids,
            basis, (const uint2*)mask32, out, n_post, n_syn);
    }
}